// Round 4
// baseline (3000.632 us; speedup 1.0000x reference)
//
#include <hip/hip_runtime.h>
#include <stdint.h>

#define B_    4096
#define H_    1024
#define T_    60
#define IN_   1028
#define KA_   1056      // IN_ padded to multiple of 32
#define G4_   4096      // 4*H
#define MLPH_ 64
#define NB_   6         // MLP batch depth / h ring size

typedef __attribute__((ext_vector_type(8))) short bf16x8;
typedef __attribute__((ext_vector_type(4))) float f32x4;
typedef __attribute__((ext_vector_type(4))) unsigned short u16x4;

#define GLOBAL_AS __attribute__((address_space(1)))
#define LDS_AS    __attribute__((address_space(3)))

__device__ __forceinline__ void gload_lds16(const void* g, void* l) {
  __builtin_amdgcn_global_load_lds((GLOBAL_AS void*)const_cast<void*>(g),
                                   (LDS_AS void*)l, 16, 0, 0);
}

__device__ __forceinline__ unsigned short f2bf(float f) {
  union { float f; unsigned int u; } v; v.f = f;
  unsigned int r = v.u + 0x7FFFu + ((v.u >> 16) & 1u);
  return (unsigned short)(r >> 16);
}

__device__ __forceinline__ float bf2f(unsigned short u) {
  union { unsigned int u; float f; } v; v.u = ((unsigned int)u) << 16;
  return v.f;
}

__device__ __forceinline__ float sigmf(float x) {
  float e = __expf(-x);
  return __builtin_amdgcn_rcpf(1.0f + e);
}

__device__ __forceinline__ float tanh_fast(float x) {
  x = fminf(fmaxf(x, -15.0f), 15.0f);
  float e = __expf(2.0f * x);
  return (e - 1.0f) * __builtin_amdgcn_rcpf(e + 1.0f);
}

// ---------------- conversion / setup kernels ----------------

__global__ void k_conv_bf16(const float* __restrict__ src,
                            unsigned short* __restrict__ dst, int n) {
  int i = blockIdx.x * blockDim.x + threadIdx.x;
  int stride = gridDim.x * blockDim.x;
  for (; i < n; i += stride) dst[i] = f2bf(src[i]);
}

// W_ih (4096 x 1028) -> bf16 padded (4096 x 1056)
__global__ void k_conv_wih(const float* __restrict__ w,
                           unsigned short* __restrict__ dst) {
  int i = blockIdx.x * blockDim.x + threadIdx.x;
  int stride = gridDim.x * blockDim.x;
  const int n = G4_ * KA_;
  for (; i < n; i += stride) {
    int r = i / KA_, k = i - r * KA_;
    dst[i] = (k < IN_) ? f2bf(w[(size_t)r * IN_ + k]) : (unsigned short)0;
  }
}

// z_aug = [z | last_pos | last_vel | zero-pad]  (4096 x 1056 bf16)
__global__ void k_build_zaug(const float* __restrict__ z,
                             const float* __restrict__ lp,
                             const float* __restrict__ lv,
                             unsigned short* __restrict__ dst) {
  int i = blockIdx.x * blockDim.x + threadIdx.x;
  int stride = gridDim.x * blockDim.x;
  const int n = B_ * KA_;
  for (; i < n; i += stride) {
    int b = i / KA_, k = i - b * KA_;
    float v;
    if (k < H_)            v = z[(size_t)b * H_ + k];
    else if (k < H_ + 2)   v = lp[b * 2 + (k - H_)];
    else if (k < IN_)      v = lv[b * 2 + (k - H_ - 2)];
    else                   v = 0.0f;
    dst[i] = f2bf(v);
  }
}

// LDS swizzle: chunk = 16 rows x 64B (1KB). gload_lds writes lane l -> l*16 (linear).
// Source pre-swizzle: lane l loads global slot (l&3)^((l>>3)&3) of row l>>2.
// Read swizzle: element (row R, slot S) lives at R*64 + (S^((R>>1)&3))*16.
// Per 8-lane phase, granules = {0,4,1,5,2,6,3,7} -> conflict-free.

// ---------------- x_gates GEMM -> interleaved bf16x4 per (b, hc) ----------------
// 128 rows x (32 hc x 4 gates); waves 2x2: wave = 64 rows x 16 hc x 4 gates.
// Double-buffered LDS, stage-early, one barrier per K-step.

__global__ __launch_bounds__(256, 4) void k_xgates(
    const unsigned short* __restrict__ zaug, const unsigned short* __restrict__ wih,
    const float* __restrict__ bih, const float* __restrict__ bhh,
    u16x4* __restrict__ xg4) {
  __shared__ unsigned short As[2][128 * 32];
  __shared__ unsigned short Bs[2][128 * 32];
  const int tid = threadIdx.x, lane = tid & 63, wave = tid >> 6;
  const int bx = blockIdx.x, by = blockIdx.y;
  const int wm = wave >> 1, wn = wave & 1;
  const int rs = lane >> 2;
  const int c16 = (((lane & 3) ^ ((lane >> 3) & 3))) * 16;   // pre-swizzled source slot
  const int rdslot = ((lane >> 4) ^ ((lane >> 1) & 3)) * 8;  // swizzled read slot (elems)

  const char* asrc0 = (const char*)zaug + ((size_t)(bx * 128 + (wave * 2 + 0) * 16 + rs) * KA_) * 2 + c16;
  const char* asrc1 = (const char*)zaug + ((size_t)(bx * 128 + (wave * 2 + 1) * 16 + rs) * KA_) * 2 + c16;
  const char* bsrc0 = (const char*)wih  + ((size_t)(wave * H_ + by * 32 +  0 + rs) * KA_) * 2 + c16;
  const char* bsrc1 = (const char*)wih  + ((size_t)(wave * H_ + by * 32 + 16 + rs) * KA_) * 2 + c16;

  f32x4 acc[4][4];   // [gate][m]
#pragma unroll
  for (int g = 0; g < 4; ++g)
#pragma unroll
    for (int m = 0; m < 4; ++m) acc[g][m] = {0.f, 0.f, 0.f, 0.f};

  // prologue: stage k-tile 0 into buf 0
  gload_lds16(asrc0, &As[0][(wave * 2 + 0) * 512]);
  gload_lds16(asrc1, &As[0][(wave * 2 + 1) * 512]);
  gload_lds16(bsrc0, &Bs[0][(wave * 2 + 0) * 512]);
  gload_lds16(bsrc1, &Bs[0][(wave * 2 + 1) * 512]);
  __syncthreads();

  const int nt = KA_ / 32;
  int cur = 0;
  for (int kk = 0; kk < nt; ++kk) {
    if (kk + 1 < nt) {
      const size_t kb = (size_t)(kk + 1) * 64;
      gload_lds16(asrc0 + kb, &As[cur ^ 1][(wave * 2 + 0) * 512]);
      gload_lds16(asrc1 + kb, &As[cur ^ 1][(wave * 2 + 1) * 512]);
      gload_lds16(bsrc0 + kb, &Bs[cur ^ 1][(wave * 2 + 0) * 512]);
      gload_lds16(bsrc1 + kb, &Bs[cur ^ 1][(wave * 2 + 1) * 512]);
    }
    bf16x8 a[4], b[4];
#pragma unroll
    for (int m = 0; m < 4; ++m)
      a[m] = *(const bf16x8*)&As[cur][(wm * 64 + m * 16 + (lane & 15)) * 32 + rdslot];
#pragma unroll
    for (int g = 0; g < 4; ++g)
      b[g] = *(const bf16x8*)&Bs[cur][((g * 2 + wn) * 16 + (lane & 15)) * 32 + rdslot];
#pragma unroll
    for (int g = 0; g < 4; ++g)
#pragma unroll
      for (int m = 0; m < 4; ++m)
        acc[g][m] = __builtin_amdgcn_mfma_f32_16x16x32_bf16(a[m], b[g], acc[g][m], 0, 0, 0);
    __syncthreads();
    cur ^= 1;
  }

  const int r0 = (lane >> 4) * 4, cl = lane & 15;
  const int hc = by * 32 + wn * 16 + cl;
  const float bi = bih[hc]        + bhh[hc];
  const float bf = bih[1024 + hc] + bhh[1024 + hc];
  const float bg = bih[2048 + hc] + bhh[2048 + hc];
  const float bo = bih[3072 + hc] + bhh[3072 + hc];
#pragma unroll
  for (int m = 0; m < 4; ++m)
#pragma unroll
    for (int j = 0; j < 4; ++j) {
      int row = bx * 128 + wm * 64 + m * 16 + r0 + j;
      u16x4 st = {f2bf(acc[0][m][j] + bi), f2bf(acc[1][m][j] + bf),
                  f2bf(acc[2][m][j] + bg), f2bf(acc[3][m][j] + bo)};
      xg4[(size_t)row * H_ + hc] = st;
    }
}

// ---------------- LSTM step: gates = xg + h @ W_hh^T, fused cell update ----------------

__global__ __launch_bounds__(256, 4) void k_step(
    const unsigned short* __restrict__ hprev, const unsigned short* __restrict__ whh,
    const u16x4* __restrict__ xg4, float* __restrict__ cbuf,
    unsigned short* __restrict__ hout) {
  __shared__ unsigned short As[2][128 * 32];
  __shared__ unsigned short Bs[2][128 * 32];
  const int tid = threadIdx.x, lane = tid & 63, wave = tid >> 6;
  const int bx = blockIdx.x, by = blockIdx.y;
  const int wm = wave >> 1, wn = wave & 1;
  const int rs = lane >> 2;
  const int c16 = (((lane & 3) ^ ((lane >> 3) & 3))) * 16;   // pre-swizzled source slot
  const int rdslot = ((lane >> 4) ^ ((lane >> 1) & 3)) * 8;  // swizzled read slot (elems)

  const char* asrc0 = (const char*)hprev + ((size_t)(bx * 128 + (wave * 2 + 0) * 16 + rs) * H_) * 2 + c16;
  const char* asrc1 = (const char*)hprev + ((size_t)(bx * 128 + (wave * 2 + 1) * 16 + rs) * H_) * 2 + c16;
  const char* bsrc0 = (const char*)whh   + ((size_t)(wave * H_ + by * 32 +  0 + rs) * H_) * 2 + c16;
  const char* bsrc1 = (const char*)whh   + ((size_t)(wave * H_ + by * 32 + 16 + rs) * H_) * 2 + c16;

  f32x4 acc[4][4];   // [gate][m]
#pragma unroll
  for (int g = 0; g < 4; ++g)
#pragma unroll
    for (int m = 0; m < 4; ++m) acc[g][m] = {0.f, 0.f, 0.f, 0.f};

  gload_lds16(asrc0, &As[0][(wave * 2 + 0) * 512]);
  gload_lds16(asrc1, &As[0][(wave * 2 + 1) * 512]);
  gload_lds16(bsrc0, &Bs[0][(wave * 2 + 0) * 512]);
  gload_lds16(bsrc1, &Bs[0][(wave * 2 + 1) * 512]);
  __syncthreads();

  const int nt = H_ / 32;
  int cur = 0;
  for (int kk = 0; kk < nt; ++kk) {
    if (kk + 1 < nt) {
      const size_t kb = (size_t)(kk + 1) * 64;
      gload_lds16(asrc0 + kb, &As[cur ^ 1][(wave * 2 + 0) * 512]);
      gload_lds16(asrc1 + kb, &As[cur ^ 1][(wave * 2 + 1) * 512]);
      gload_lds16(bsrc0 + kb, &Bs[cur ^ 1][(wave * 2 + 0) * 512]);
      gload_lds16(bsrc1 + kb, &Bs[cur ^ 1][(wave * 2 + 1) * 512]);
    }
    bf16x8 a[4], b[4];
#pragma unroll
    for (int m = 0; m < 4; ++m)
      a[m] = *(const bf16x8*)&As[cur][(wm * 64 + m * 16 + (lane & 15)) * 32 + rdslot];
#pragma unroll
    for (int g = 0; g < 4; ++g)
      b[g] = *(const bf16x8*)&Bs[cur][((g * 2 + wn) * 16 + (lane & 15)) * 32 + rdslot];
#pragma unroll
    for (int g = 0; g < 4; ++g)
#pragma unroll
      for (int m = 0; m < 4; ++m)
        acc[g][m] = __builtin_amdgcn_mfma_f32_16x16x32_bf16(a[m], b[g], acc[g][m], 0, 0, 0);
    __syncthreads();
    cur ^= 1;
  }

  const int r0 = (lane >> 4) * 4, cl = lane & 15;
  const int hc = by * 32 + wn * 16 + cl;
#pragma unroll
  for (int m = 0; m < 4; ++m)
#pragma unroll
    for (int j = 0; j < 4; ++j) {
      int row = bx * 128 + wm * 64 + m * 16 + r0 + j;   // batch index
      size_t ci = (size_t)row * H_ + hc;
      u16x4 xv = xg4[ci];
      float iv = sigmf(acc[0][m][j] + bf2f(xv[0]));
      float fv = sigmf(acc[1][m][j] + bf2f(xv[1]));
      float gv = tanh_fast(acc[2][m][j] + bf2f(xv[2]));
      float ov = sigmf(acc[3][m][j] + bf2f(xv[3]));
      float cv = fv * cbuf[ci] + iv * gv;
      cbuf[ci] = cv;
      hout[ci] = f2bf(ov * tanh_fast(cv));
    }
}

// ---------------- batched MLP over NB_ steps ----------------

__global__ __launch_bounds__(256) void k_mlp(
    const unsigned short* __restrict__ hring, const unsigned short* __restrict__ w1,
    const float* __restrict__ b1, const float* __restrict__ w2,
    const float* __restrict__ b2, float* __restrict__ delta, int t0) {
  __shared__ unsigned short As[64 * 32];
  __shared__ unsigned short Bs[64 * 32];
  __shared__ float hid[64][65];
  const int tid = threadIdx.x, lane = tid & 63, wave = tid >> 6;
  const int bx = blockIdx.x;
  const unsigned short* h = hring + (size_t)blockIdx.y * B_ * H_;
  const int t = t0 + blockIdx.y;
  const int rs = lane >> 2;
  const int c16 = (((lane & 3) ^ ((lane >> 3) & 3))) * 16;
  const int rdslot = ((lane >> 4) ^ ((lane >> 1) & 3)) * 8;

  f32x4 acc[4];
#pragma unroll
  for (int n = 0; n < 4; ++n) acc[n] = {0.f, 0.f, 0.f, 0.f};

  for (int kk = 0; kk < H_ / 32; ++kk) {
    const int k0 = kk * 32;
    __syncthreads();
    {
      int row = bx * 64 + wave * 16 + rs;
      gload_lds16((const char*)h + ((size_t)row * H_ + k0) * 2 + c16,
                  (char*)As + wave * 1024);
    }
    {
      int jj = wave * 16 + rs;
      gload_lds16((const char*)w1 + ((size_t)jj * H_ + k0) * 2 + c16,
                  (char*)Bs + wave * 1024);
    }
    __syncthreads();
    bf16x8 a = *(const bf16x8*)&As[(wave * 16 + (lane & 15)) * 32 + rdslot];
#pragma unroll
    for (int n = 0; n < 4; ++n) {
      bf16x8 b = *(const bf16x8*)&Bs[(n * 16 + (lane & 15)) * 32 + rdslot];
      acc[n] = __builtin_amdgcn_mfma_f32_16x16x32_bf16(a, b, acc[n], 0, 0, 0);
    }
  }

  const int r0 = (lane >> 4) * 4, cl = lane & 15;
#pragma unroll
  for (int n = 0; n < 4; ++n)
#pragma unroll
    for (int j = 0; j < 4; ++j) {
      int row = wave * 16 + r0 + j;     // local row 0..63
      int col = n * 16 + cl;            // hidden unit 0..63
      hid[row][col] = fmaxf(acc[n][j] + b1[col], 0.0f);
    }
  __syncthreads();

  if (tid < 128) {
    int r = tid >> 1, d = tid & 1;
    float s = b2[d];
#pragma unroll 8
    for (int k2 = 0; k2 < 64; ++k2) s += hid[r][k2] * w2[d * 64 + k2];
    delta[((size_t)(bx * 64 + r) * T_ + t) * 2 + d] = s;
  }
}

// ---------------- final cumsum over T + last_pos ----------------

__global__ void k_cumsum(const float* __restrict__ delta,
                         const float* __restrict__ lp, float* __restrict__ out) {
  int id = blockIdx.x * blockDim.x + threadIdx.x;
  if (id >= B_ * 2) return;
  int b = id >> 1, d = id & 1;
  float cum = lp[b * 2 + d];
  size_t base = (size_t)b * T_ * 2 + d;
  for (int t = 0; t < T_; ++t) {
    cum += delta[base + t * 2];
    out[base + t * 2] = cum;
  }
}

// ---------------- launch ----------------

extern "C" void kernel_launch(void* const* d_in, const int* in_sizes, int n_in,
                              void* d_out, int out_size, void* d_ws, size_t ws_size,
                              hipStream_t stream) {
  const float* z   = (const float*)d_in[0];
  const float* lv  = (const float*)d_in[1];
  const float* lp  = (const float*)d_in[2];
  const float* Wih = (const float*)d_in[3];
  const float* Whh = (const float*)d_in[4];
  const float* bih = (const float*)d_in[5];
  const float* bhh = (const float*)d_in[6];
  const float* W1  = (const float*)d_in[7];
  const float* b1  = (const float*)d_in[8];
  const float* W2  = (const float*)d_in[9];
  const float* b2  = (const float*)d_in[10];
  float* out = (float*)d_out;

  char* ws = (char*)d_ws;
  size_t off = 0;
  u16x4*          xg4    = (u16x4*)(ws + off);          off += (size_t)B_ * H_ * 8;       // 33554432
  unsigned short* whh_bf = (unsigned short*)(ws + off); off += (size_t)G4_ * H_ * 2;      //  8388608
  unsigned short* wih_bf = (unsigned short*)(ws + off); off += (size_t)G4_ * KA_ * 2;     //  8650752
  unsigned short* zaug   = (unsigned short*)(ws + off); off += (size_t)B_ * KA_ * 2;      //  8650752
  unsigned short* w1_bf  = (unsigned short*)(ws + off); off += (size_t)MLPH_ * H_ * 2;    //   131072
  unsigned short* hring  = (unsigned short*)(ws + off); off += (size_t)NB_ * B_ * H_ * 2; // 50331648
  float*          cbuf   = (float*)(ws + off);          off += (size_t)B_ * H_ * 4;       // 16777216
  float*          delta  = (float*)(ws + off);          off += (size_t)B_ * T_ * 2 * 4;   //  1966080
  // total 128450560 bytes

  const size_t BH = (size_t)B_ * H_;

  // zero c and the h(-1) slot (= slot NB_-1 of the ring)
  hipMemsetAsync(hring + (NB_ - 1) * BH, 0, BH * 2, stream);
  hipMemsetAsync(cbuf, 0, BH * 4, stream);

  k_conv_bf16 <<<2048, 256, 0, stream>>>(Whh, whh_bf, G4_ * H_);
  k_conv_wih  <<<2048, 256, 0, stream>>>(Wih, wih_bf);
  k_build_zaug<<<2048, 256, 0, stream>>>(z, lp, lv, zaug);
  k_conv_bf16 <<<256, 256, 0, stream>>>(W1, w1_bf, MLPH_ * H_);

  k_xgates<<<dim3(32, 32), 256, 0, stream>>>(zaug, wih_bf, bih, bhh, xg4);

  for (int t = 0; t < T_; ++t) {
    const unsigned short* hp = hring + (size_t)((t + NB_ - 1) % NB_) * BH;
    unsigned short*       hc = hring + (size_t)(t % NB_) * BH;
    k_step<<<dim3(32, 32), 256, 0, stream>>>(hp, whh_bf, xg4, cbuf, hc);
    if ((t % NB_) == NB_ - 1)
      k_mlp<<<dim3(64, NB_), 256, 0, stream>>>(hring, w1_bf, b1, W2, b2, delta, t - (NB_ - 1));
  }

  k_cumsum<<<32, 256, 0, stream>>>(delta, lp, out);
}